// Round 6
// baseline (715.261 us; speedup 1.0000x reference)
//
#include <hip/hip_runtime.h>

// ChebNet on MI355X — Round 11: full-cache-line z requests (32-wide slices).
//
// R8/R9/R10 all floor at ~60 us with every pipe <60% busy, and layer2
// (half the z-requests/CU) takes the SAME time as layer3 -> the gather is
// line-fill (MSHR) limited: 1 fill per edge per 16-feature slice, 64B each.
// R11 makes each fill a full 128B line: 32-feature slices, 8-lane groups x
// float4 (one 128B row per edge request). Layer2: z = plain [N][32] (no
// slicing, 6.4 MB). Layer3: 2 slices x 6.4 MB, 4 XCDs each. Fill count
// halves; z spills 4MB L2 into L3 (acceptable: latency x1.5 < fills x2).
// Per-(node,feature) fmaf chain still sequential in CSR order -> bit-exact.

constexpr int N_NODES  = 50000;
constexpr int N_EDGES  = 1600000;
constexpr int N_GRAPHS = 128;

constexpr int NF   = N_NODES * 32;         // floats per 32-feature slice block
constexpr int SB32 = (N_NODES + 31) / 32;  // 1563 node-groups of 32

constexpr int NB_H = 256;                 // histogram/place blocks
constexpr int EPB  = N_EDGES / NB_H;      // 6250 edges per block (exact)
constexpr int NW   = (N_NODES + 3) / 4;   // 12500 packed words (4 u8 bins each)

static inline int cdiv(long long a, int b) { return (int)((a + b - 1) / b); }

// ---- CSR build (atomic-free at device scope) ---------------------------

// Fused src+dst degree histogram: 2 x 50 KB LDS (dynamic), edge list read once.
__global__ __launch_bounds__(256) void hist2_kernel(const int* __restrict__ src,
                                                    const int* __restrict__ dst,
                                                    unsigned* __restrict__ Hs,
                                                    unsigned* __restrict__ Hd) {
    extern __shared__ unsigned lds2[];  // [2*NW]
    unsigned* ls = lds2;
    unsigned* ld_ = lds2 + NW;
    const int b = blockIdx.x, t = threadIdx.x;
    for (int i = t; i < 2 * NW; i += 256) lds2[i] = 0;
    __syncthreads();
    const int e0 = b * EPB, e1 = e0 + EPB;
    for (int e = e0 + t; e < e1; e += 256) {
        int s = src[e], d = dst[e];
        if (s != d) {
            atomicAdd(&ls[s >> 2], 1u << (8 * (s & 3)));
            atomicAdd(&ld_[d >> 2], 1u << (8 * (d & 3)));
        }
    }
    __syncthreads();
    unsigned* HsB = Hs + (size_t)b * NW;
    unsigned* HdB = Hd + (size_t)b * NW;
    for (int i = t; i < NW; i += 256) { HsB[i] = ls[i]; HdB[i] = ld_[i]; }
}

__global__ void merge_src_kernel(const unsigned* __restrict__ H, float* __restrict__ dinv) {
    int i = blockIdx.x * blockDim.x + threadIdx.x;
    if (i >= NW) return;
    unsigned s0 = 0, s1 = 0, s2 = 0, s3 = 0;
    for (int b = 0; b < NB_H; ++b) {
        unsigned v = H[(size_t)b * NW + i];
        s0 += v & 0xff; s1 += (v >> 8) & 0xff; s2 += (v >> 16) & 0xff; s3 += v >> 24;
    }
    dinv[4 * i + 0] = s0 ? rsqrtf((float)s0) : 0.f;
    dinv[4 * i + 1] = s1 ? rsqrtf((float)s1) : 0.f;
    dinv[4 * i + 2] = s2 ? rsqrtf((float)s2) : 0.f;
    dinv[4 * i + 3] = s3 ? rsqrtf((float)s3) : 0.f;
}

__global__ void merge_dst_kernel(const unsigned* __restrict__ H, unsigned* __restrict__ P,
                                 int* __restrict__ cnt) {
    int i = blockIdx.x * blockDim.x + threadIdx.x;
    if (i >= NW) return;
    unsigned p0 = 0, p1 = 0, p2 = 0, p3 = 0;
    for (int b = 0; b < NB_H; ++b) {
        size_t idx = (size_t)b * NW + i;
        unsigned v = H[idx];
        P[idx] = p0 | (p1 << 8) | (p2 << 16) | (p3 << 24);
        p0 += v & 0xff; p1 += (v >> 8) & 0xff; p2 += (v >> 16) & 0xff; p3 += v >> 24;
    }
    cnt[4 * i + 0] = (int)p0; cnt[4 * i + 1] = (int)p1;
    cnt[4 * i + 2] = (int)p2; cnt[4 * i + 3] = (int)p3;
}

// ---- 3-phase scan ------------------------------------------------------

constexpr int SCAN_B = 256;
constexpr int SCAN_NB = (N_NODES + SCAN_B - 1) / SCAN_B;  // 196

__global__ void scan_block_kernel(const int* __restrict__ cnt, int* __restrict__ row,
                                  int* __restrict__ bsum) {
    __shared__ int buf[SCAN_B];
    int t = threadIdx.x;
    int i = blockIdx.x * SCAN_B + t;
    buf[t] = (i < N_NODES) ? cnt[i] : 0;
    __syncthreads();
    for (int off = 1; off < SCAN_B; off <<= 1) {
        int a = (t >= off) ? buf[t - off] : 0;
        __syncthreads();
        buf[t] += a;
        __syncthreads();
    }
    if (i < N_NODES) row[i + 1] = buf[t];
    if (t == SCAN_B - 1) bsum[blockIdx.x] = buf[t];
    if (i == 0) row[0] = 0;
}

__global__ void scan_sums_kernel(int* __restrict__ bsum) {
    __shared__ int buf[SCAN_NB];
    int t = threadIdx.x;
    if (t < SCAN_NB) buf[t] = bsum[t];
    __syncthreads();
    for (int off = 1; off < SCAN_NB; off <<= 1) {
        int a = (t >= off && t < SCAN_NB) ? buf[t - off] : 0;
        __syncthreads();
        if (t < SCAN_NB) buf[t] += a;
        __syncthreads();
    }
    if (t < SCAN_NB) bsum[t] = buf[t];
}

__global__ void scan_add_kernel(int* __restrict__ row, const int* __restrict__ bsum) {
    int i = blockIdx.x * SCAN_B + threadIdx.x;
    if (blockIdx.x > 0 && i < N_NODES) row[i + 1] += bsum[blockIdx.x - 1];
}

__global__ __launch_bounds__(256) void place_kernel(const int* __restrict__ src,
                                                    const int* __restrict__ dst,
                                                    const float* __restrict__ dinv,
                                                    const int* __restrict__ row,
                                                    const unsigned* __restrict__ P,
                                                    float2* __restrict__ csr) {
    __shared__ unsigned lds[NW];
    const int b = blockIdx.x, t = threadIdx.x;
    for (int i = t; i < NW; i += 256) lds[i] = 0;
    __syncthreads();
    const int e0 = b * EPB, e1 = e0 + EPB;
    const unsigned* Pb = P + (size_t)b * NW;
    for (int e = e0 + t; e < e1; e += 256) {
        int s = src[e], d = dst[e];
        if (s != d) {
            float w = -dinv[s] * dinv[d];
            int sh = 8 * (d & 3);
            unsigned old = atomicAdd(&lds[d >> 2], 1u << sh);
            unsigned cur = (old >> sh) & 0xff;
            unsigned pref = (Pb[d >> 2] >> sh) & 0xff;
            int pos = row[d] + (int)pref + (int)cur;
            csr[pos] = make_float2(w, __int_as_float(s));
        }
    }
}

// ---- L(z) gathers ------------------------------------------------------

// Layer 1 (F=4): thread per (node, feature) — 200K threads. Sequential
// per-(node,feature) fmaf order -> bit-exact.
__global__ void gatherF4_kernel(const int* __restrict__ row, const float2* __restrict__ csr,
                                const float* __restrict__ z, const float* __restrict__ prev,
                                float* __restrict__ out, float alpha, float beta) {
    int idx = blockIdx.x * blockDim.x + threadIdx.x;
    int node = idx >> 2;
    int lane = idx & 3;
    if (node >= N_NODES) return;
    int e0 = row[node], e1 = row[node + 1];
    float acc = 0.f;
#pragma unroll 4
    for (int e = e0; e < e1; ++e) {
        float2 ew = csr[e];  // 4 lanes same addr: hw broadcast
        acc = fmaf(ew.x, z[(size_t)__float_as_int(ew.y) * 4 + lane], acc);
    }
    float r = alpha * acc;
    if (beta != 0.f) r = fmaf(beta, prev[(size_t)node * 4 + lane], r);
    out[(size_t)node * 4 + lane] = r;
}

// Layers 2/3: 32-feature slices, feature-blocked [NSLICE][N][32] (128B rows).
// Block = 256 threads = 32 nodes, 8-lane groups x float4: each edge request
// is one full 128B line (halves line-fill count vs 16-wide slices -> the
// MSHR-limited floor halves). NSLICE=1 (layer2): plain [N][32], no XCD
// pinning. NSLICE=2 (layer3): slice pinned to 4 XCDs via bid%8. CSR staged
// into 2048-edge LDS windows with nt loads (HBM latency paid once/block).
// Sequential per-(node,feature) edge order -> bit-exact.
template <int NSLICE>
__global__ __launch_bounds__(256) void gather32_kernel(
        const int* __restrict__ row, const float2* __restrict__ csr,
        const float* __restrict__ z, const float* __restrict__ prev,
        float* __restrict__ out, float alpha, float beta) {
    constexpr int CAP = 2048;  // edges per LDS window (16 KB)
    __shared__ unsigned long long elds[CAP];
    int sblk, slice;
    if constexpr (NSLICE == 1) {
        sblk = blockIdx.x;
        slice = 0;
    } else {
        const int xcd = blockIdx.x & 7;
        slice = xcd >> 2;                        // 4 XCDs per slice
        sblk = (blockIdx.x >> 3) * 4 + (xcd & 3);
    }
    if (sblk >= SB32) return;
    const int t = threadIdx.x;
    const int n = sblk * 32 + (t >> 3);  // 32 nodes per block, 8 lanes each
    const int lane = t & 7;              // feature quad within 32-slice
    const bool valid = (n < N_NODES);
    const float* zs = z + (size_t)slice * NF + 4 * lane;
    const int e0 = valid ? row[n] : 0;
    const int e1 = valid ? row[n + 1] : 0;
    const int nb0 = sblk * 32;
    const int b0 = row[nb0];
    const int b1 = row[min(nb0 + 32, N_NODES)];
    float4 acc = make_float4(0.f, 0.f, 0.f, 0.f);
    for (int w0 = b0; w0 < b1; w0 += CAP) {
        const int w1 = min(w0 + CAP, b1);
        __syncthreads();  // previous window fully consumed
        for (int e = w0 + t; e < w1; e += 256)
            elds[e - w0] = __builtin_nontemporal_load((const unsigned long long*)csr + e);
        __syncthreads();
        const int g0 = max(e0, w0), g1 = min(e1, w1);
#pragma unroll 8
        for (int e = g0; e < g1; ++e) {
            unsigned long long raw = elds[e - w0];  // 8-lane broadcast
            float w = __uint_as_float((unsigned)raw);
            int s = (int)(raw >> 32);
            const float4 zz = *(const float4*)(zs + (size_t)s * 32);
            acc.x = fmaf(w, zz.x, acc.x);
            acc.y = fmaf(w, zz.y, acc.y);
            acc.z = fmaf(w, zz.z, acc.z);
            acc.w = fmaf(w, zz.w, acc.w);
        }
    }
    if (valid) {
        float4 r = make_float4(alpha * acc.x, alpha * acc.y,
                               alpha * acc.z, alpha * acc.w);
        size_t off = (size_t)slice * NF + (size_t)n * 32 + 4 * lane;
        if (beta != 0.f) {
            r.x = fmaf(beta, __builtin_nontemporal_load(prev + off), r.x);
            r.y = fmaf(beta, __builtin_nontemporal_load(prev + off + 1), r.y);
            r.z = fmaf(beta, __builtin_nontemporal_load(prev + off + 2), r.z);
            r.w = fmaf(beta, __builtin_nontemporal_load(prev + off + 3), r.w);
        }
        __builtin_nontemporal_store(r.x, out + off);
        __builtin_nontemporal_store(r.y, out + off + 1);
        __builtin_nontemporal_store(r.z, out + off + 2);
        __builtin_nontemporal_store(r.w, out + off + 3);
    }
}

// ---- combine: out[n,o] = relu(b[o] + sum_k T_k[n,:] @ W[k,:,o]) --------
// Inputs X,T1..T4 are feature-blocked [FI/32][N][32]; output written blocked
// [FO/32][N][32]. Each block reads/writes only its own 64 node rows, so the
// layer-3 in-place write to T1 is race-free.

template <int FI>
__global__ __launch_bounds__(256, 4) void combine64_kernel(
        const float* __restrict__ X, const float* __restrict__ T1,
        const float* __restrict__ T2, const float* __restrict__ T3,
        const float* __restrict__ T4, const float* __restrict__ W,
        const float* __restrict__ b, float* __restrict__ out) {
    constexpr int FO = 64;
    constexpr int TS = FI + 4;
    __shared__ float Ts[64 * TS];
    __shared__ float Ws[FI * FO];
    const int t = threadIdx.x;
    const int tn = t & 15;
    const int to = t >> 4;
    const int n_base = blockIdx.x * 64;
    const float* Tk[5] = {X, T1, T2, T3, T4};

    float acc[4][4];
    {
        const float4 bb = *(const float4*)(b + 4 * to);
#pragma unroll
        for (int i = 0; i < 4; ++i) {
            acc[i][0] = bb.x; acc[i][1] = bb.y; acc[i][2] = bb.z; acc[i][3] = bb.w;
        }
    }

#pragma unroll
    for (int k = 0; k < 5; ++k) {
        __syncthreads();
        {
            const float* base = Tk[k];
            constexpr int NV = 64 * FI / 4;
#pragma unroll
            for (int idx = t; idx < NV; idx += 256) {
                int r = idx / (FI / 4), c = idx % (FI / 4);
                int s = c >> 3;            // 32-wide feature block
                int j = (c & 7) * 4;       // offset within block
                float4 v = make_float4(0.f, 0.f, 0.f, 0.f);
                if (n_base + r < N_NODES)
                    v = *(const float4*)(base + (size_t)s * NF +
                                         (size_t)(n_base + r) * 32 + j);
                *(float4*)(Ts + r * TS + 4 * c) = v;  // f = 32*s + j = 4*c
            }
            const float4* w4 = (const float4*)(W + (size_t)k * FI * FO);
            constexpr int WV = FI * FO / 4;
#pragma unroll
            for (int idx = t; idx < WV; idx += 256) *(float4*)(Ws + 4 * idx) = w4[idx];
        }
        __syncthreads();
#pragma unroll 4
        for (int f0 = 0; f0 < FI; f0 += 4) {
            float tv[4][4];
#pragma unroll
            for (int i = 0; i < 4; ++i) {
                float4 q = *(const float4*)(Ts + (tn + 16 * i) * TS + f0);
                tv[i][0] = q.x; tv[i][1] = q.y; tv[i][2] = q.z; tv[i][3] = q.w;
            }
#pragma unroll
            for (int j = 0; j < 4; ++j) {
                float4 w = *(const float4*)(Ws + (f0 + j) * FO + 4 * to);
#pragma unroll
                for (int i = 0; i < 4; ++i) {
                    acc[i][0] = fmaf(tv[i][j], w.x, acc[i][0]);
                    acc[i][1] = fmaf(tv[i][j], w.y, acc[i][1]);
                    acc[i][2] = fmaf(tv[i][j], w.z, acc[i][2]);
                    acc[i][3] = fmaf(tv[i][j], w.w, acc[i][3]);
                }
            }
        }
    }
    __syncthreads();
#pragma unroll
    for (int i = 0; i < 4; ++i) {
        int n = n_base + tn + 16 * i;
        if (n < N_NODES) {
            float4 r = make_float4(fmaxf(acc[i][0], 0.f), fmaxf(acc[i][1], 0.f),
                                   fmaxf(acc[i][2], 0.f), fmaxf(acc[i][3], 0.f));
            int s = to >> 3;            // output 32-wide block
            int j = (to & 7) * 4;
            *(float4*)(out + (size_t)s * NF + (size_t)n * 32 + j) = r;
        }
    }
}

// Layer 1 combine: X,T row-major [N][4], output plain row-major [N][32]
// (= 32-wide block layout with NSLICE=1).
__global__ void combine432_kernel(const float* __restrict__ X, const float* __restrict__ T1,
                                  const float* __restrict__ T2, const float* __restrict__ T3,
                                  const float* __restrict__ T4, const float* __restrict__ W,
                                  const float* __restrict__ b, float* __restrict__ out) {
    __shared__ float Ws[5 * 4 * 32];
    int t = threadIdx.x;
    for (int i = t; i < 5 * 4 * 32; i += 256) Ws[i] = W[i];
    __syncthreads();
    int node = blockIdx.x * 8 + (t >> 5);
    int o = t & 31;
    if (node >= N_NODES) return;
    const float4* Tk[5] = {(const float4*)X, (const float4*)T1, (const float4*)T2,
                           (const float4*)T3, (const float4*)T4};
    float acc = b[o];
#pragma unroll
    for (int k = 0; k < 5; ++k) {
        float4 q = Tk[k][node];
        const float* w = Ws + k * 128 + o;
        acc = fmaf(q.x, w[0], acc);
        acc = fmaf(q.y, w[32], acc);
        acc = fmaf(q.z, w[64], acc);
        acc = fmaf(q.w, w[96], acc);
    }
    out[(size_t)node * 32 + o] = fmaxf(acc, 0.f);
}

// ---- pooling + MLP -----------------------------------------------------

// h is feature-blocked [2][N][32] (layer-3 output).
__global__ void pool_kernel(const float* __restrict__ h, const int* __restrict__ batch,
                            float* __restrict__ pooled, float* __restrict__ cntf) {
    int wid = blockIdx.x * (blockDim.x / 64) + (threadIdx.x >> 6);
    int lane = threadIdx.x & 63;
    int nwaves = gridDim.x * (blockDim.x / 64);
    int per = (N_NODES + nwaves - 1) / nwaves;
    int n0 = wid * per;
    int n1 = min(n0 + per, N_NODES);
    if (n0 >= n1) return;
    const float* hp = h + (size_t)(lane >> 5) * NF + (lane & 31);
    int cur = batch[n0];
    float acc = 0.f;
    int c = 0;
    for (int n = n0; n < n1; ++n) {
        int g = batch[n];
        if (g != cur) {
            atomicAdd(&pooled[cur * 64 + lane], acc);
            if (lane == 0) atomicAdd(&cntf[cur], (float)c);
            acc = 0.f; c = 0; cur = g;
        }
        acc += hp[(size_t)n * 32];
        ++c;
    }
    atomicAdd(&pooled[cur * 64 + lane], acc);
    if (lane == 0) atomicAdd(&cntf[cur], (float)c);
}

__global__ void fc_kernel(const float* __restrict__ pooled, const float* __restrict__ cnt,
                          const float* __restrict__ w1, const float* __restrict__ b1,
                          const float* __restrict__ w2, const float* __restrict__ b2,
                          float* __restrict__ out) {
    int g = blockIdx.x;
    int t = threadIdx.x;
    __shared__ float hid[32];
    float c = fmaxf(cnt[g], 1.0f);
    float acc = b1[t];
    for (int f = 0; f < 64; ++f) acc = fmaf(pooled[g * 64 + f] / c, w1[f * 32 + t], acc);
    hid[t] = fmaxf(acc, 0.f);
    __syncthreads();
    if (t == 0) {
        float acc2 = b2[0];
        for (int o = 0; o < 32; ++o) acc2 = fmaf(hid[o], w2[o], acc2);
        out[g] = acc2;
    }
}

// ---- host orchestration ------------------------------------------------

template <int FI, int FO>
static void run_layer(const int* row, const float2* csr, const float* X,
                      float* T1, float* T2, float* T3, float* T4,
                      const float* W, const float* b, float* out, hipStream_t stream) {
    if constexpr (FI == 4) {
        dim3 g(cdiv((long long)N_NODES * 4, 256)), blk(256);
        hipLaunchKernelGGL(gatherF4_kernel, g, blk, 0, stream, row, csr, X,  X,  T1, 1.f, 0.f);
        hipLaunchKernelGGL(gatherF4_kernel, g, blk, 0, stream, row, csr, T1, X,  T2, 2.f, -1.f);
        hipLaunchKernelGGL(gatherF4_kernel, g, blk, 0, stream, row, csr, T2, T1, T3, 2.f, -1.f);
        hipLaunchKernelGGL(gatherF4_kernel, g, blk, 0, stream, row, csr, T3, T2, T4, 2.f, -1.f);
    } else {
        constexpr int NSLICE = FI / 32;
        dim3 g(NSLICE == 1 ? SB32 : cdiv(SB32, 4) * 8), blk(256);
        hipLaunchKernelGGL((gather32_kernel<NSLICE>), g, blk, 0, stream, row, csr, X,  X,  T1, 1.f, 0.f);
        hipLaunchKernelGGL((gather32_kernel<NSLICE>), g, blk, 0, stream, row, csr, T1, X,  T2, 2.f, -1.f);
        hipLaunchKernelGGL((gather32_kernel<NSLICE>), g, blk, 0, stream, row, csr, T2, T1, T3, 2.f, -1.f);
        hipLaunchKernelGGL((gather32_kernel<NSLICE>), g, blk, 0, stream, row, csr, T3, T2, T4, 2.f, -1.f);
    }
    if constexpr (FO == 64) {
        hipLaunchKernelGGL((combine64_kernel<FI>), dim3(cdiv(N_NODES, 64)), dim3(256), 0,
                           stream, X, T1, T2, T3, T4, W, b, out);
    } else {
        hipLaunchKernelGGL(combine432_kernel, dim3(cdiv(N_NODES, 8)), dim3(256), 0,
                           stream, X, T1, T2, T3, T4, W, b, out);
    }
}

extern "C" void kernel_launch(void* const* d_in, const int* in_sizes, int n_in,
                              void* d_out, int out_size, void* d_ws, size_t ws_size,
                              hipStream_t stream) {
    const float* x    = (const float*)d_in[0];
    const int*   ei   = (const int*)d_in[1];
    const int*   batch= (const int*)d_in[2];
    const float* W1   = (const float*)d_in[4];
    const float* b1   = (const float*)d_in[5];
    const float* W2   = (const float*)d_in[6];
    const float* b2   = (const float*)d_in[7];
    const float* W3   = (const float*)d_in[8];
    const float* b3   = (const float*)d_in[9];
    const float* fcw1 = (const float*)d_in[10];
    const float* fcb1 = (const float*)d_in[11];
    const float* fcw2 = (const float*)d_in[12];
    const float* fcb2 = (const float*)d_in[13];

    const int* src = ei;
    const int* dst = ei + N_EDGES;

    float* base = (float*)d_ws;
    float*  dinv   = base + 0;                      // 50000
    int*    cnt_i  = (int*)(base + 50000);          // 50000
    int*    row    = (int*)(base + 100000);         // 50004
    int*    bsum   = (int*)(base + 150004);         // 252
    float2* csr    = (float2*)(base + 150256);      // 1.6M float2
    float*  T1     = base + 3350256;
    float*  T2     = base + 6550256;
    float*  T3     = base + 9750256;
    float*  T4     = base + 12950256;
    float*  H1     = T4 + 1600000;                  // layer1 out, [N][32] (1.6M)
    float*  H2     = base + 16150256;               // layer2 out, [2][N][32] (3.2M)
    float*  pooled = base + 19350256;
    float*  cntf   = base + 19358448;

    unsigned* Hs = (unsigned*)T1;  // build-phase scratch aliases T1..T3
    unsigned* Hd = (unsigned*)T2;
    unsigned* P  = (unsigned*)T3;

    hipLaunchKernelGGL(hist2_kernel, dim3(NB_H), dim3(256), 2 * NW * sizeof(unsigned),
                       stream, src, dst, Hs, Hd);
    hipLaunchKernelGGL(merge_src_kernel, dim3(cdiv(NW, 256)), dim3(256), 0, stream, Hs, dinv);
    hipLaunchKernelGGL(merge_dst_kernel, dim3(cdiv(NW, 256)), dim3(256), 0, stream, Hd, P, cnt_i);
    hipLaunchKernelGGL(scan_block_kernel, dim3(SCAN_NB), dim3(SCAN_B), 0, stream, cnt_i, row, bsum);
    hipLaunchKernelGGL(scan_sums_kernel, dim3(1), dim3(256), 0, stream, bsum);
    hipLaunchKernelGGL(scan_add_kernel, dim3(SCAN_NB), dim3(SCAN_B), 0, stream, row, bsum);
    hipLaunchKernelGGL(place_kernel, dim3(NB_H), dim3(256), 0, stream,
                       src, dst, dinv, row, P, csr);

    run_layer<4, 32>(row, csr, x,  T1, T2, T3, T4, W1, b1, H1, stream);
    run_layer<32, 64>(row, csr, H1, T1, T2, T3, T4, W2, b2, H2, stream);
    // layer 3 writes blocked output in place into T1 (race-free: each combine
    // block reads/writes only its own 64 node rows).
    run_layer<64, 64>(row, csr, H2, T1, T2, T3, T4, W3, b3, T1, stream);

    hipMemsetAsync(pooled, 0, (8192 + 128) * sizeof(float), stream);
    hipLaunchKernelGGL(pool_kernel, dim3(128), dim3(256), 0, stream, T1, batch, pooled, cntf);
    hipLaunchKernelGGL(fc_kernel, dim3(N_GRAPHS), dim3(32), 0, stream,
                       pooled, cntf, fcw1, fcb1, fcw2, fcb2, (float*)d_out);
}

// Round 7
// 672.495 us; speedup vs baseline: 1.0636x; 1.0636x over previous
//
#include <hip/hip_runtime.h>

// ChebNet on MI355X — Round 12: force 4-deep load pipelining in gather16.
//
// R11 post-mortem: 32-wide slices left the L2 (6.4MB>4MB) -> FETCH 168MB,
// genuinely HBM-bound at 3.2 TB/s. Reverted. R10's regime (46MB, L2-hit)
// is right; its limiter is in-flight loads: VGPR=28 proves the compiler
// kept only ~2 z-loads outstanding despite unroll-8 (8 float4 would need
// 32+ VGPRs). R12 = R10 with the inner loop hand-batched: 4 edges' float4
// z-values loaded into NAMED temporaries, then fmaf'd strictly in edge
// order (bit-exact; +0 pads unchanged). Doubles per-thread MLP; compiler
// must allocate the registers. Everything else identical to R10.

constexpr int N_NODES  = 50000;
constexpr int N_EDGES  = 1600000;
constexpr int N_GRAPHS = 128;

constexpr int N16  = N_NODES * 16;         // floats per 16-feature slice block
constexpr int SB32 = (N_NODES + 31) / 32;  // 1563 node-groups of 32

constexpr int NB_H = 256;                 // histogram/place blocks
constexpr int EPB  = N_EDGES / NB_H;      // 6250 edges per block (exact)
constexpr int NW   = (N_NODES + 3) / 4;   // 12500 packed words (4 u8 bins each)

static inline int cdiv(long long a, int b) { return (int)((a + b - 1) / b); }

// ---- CSR build (atomic-free at device scope) ---------------------------

// Fused src+dst degree histogram: 2 x 50 KB LDS (dynamic), edge list read once.
__global__ __launch_bounds__(256) void hist2_kernel(const int* __restrict__ src,
                                                    const int* __restrict__ dst,
                                                    unsigned* __restrict__ Hs,
                                                    unsigned* __restrict__ Hd) {
    extern __shared__ unsigned lds2[];  // [2*NW]
    unsigned* ls = lds2;
    unsigned* ld_ = lds2 + NW;
    const int b = blockIdx.x, t = threadIdx.x;
    for (int i = t; i < 2 * NW; i += 256) lds2[i] = 0;
    __syncthreads();
    const int e0 = b * EPB, e1 = e0 + EPB;
    for (int e = e0 + t; e < e1; e += 256) {
        int s = src[e], d = dst[e];
        if (s != d) {
            atomicAdd(&ls[s >> 2], 1u << (8 * (s & 3)));
            atomicAdd(&ld_[d >> 2], 1u << (8 * (d & 3)));
        }
    }
    __syncthreads();
    unsigned* HsB = Hs + (size_t)b * NW;
    unsigned* HdB = Hd + (size_t)b * NW;
    for (int i = t; i < NW; i += 256) { HsB[i] = ls[i]; HdB[i] = ld_[i]; }
}

__global__ void merge_src_kernel(const unsigned* __restrict__ H, float* __restrict__ dinv) {
    int i = blockIdx.x * blockDim.x + threadIdx.x;
    if (i >= NW) return;
    unsigned s0 = 0, s1 = 0, s2 = 0, s3 = 0;
    for (int b = 0; b < NB_H; ++b) {
        unsigned v = H[(size_t)b * NW + i];
        s0 += v & 0xff; s1 += (v >> 8) & 0xff; s2 += (v >> 16) & 0xff; s3 += v >> 24;
    }
    dinv[4 * i + 0] = s0 ? rsqrtf((float)s0) : 0.f;
    dinv[4 * i + 1] = s1 ? rsqrtf((float)s1) : 0.f;
    dinv[4 * i + 2] = s2 ? rsqrtf((float)s2) : 0.f;
    dinv[4 * i + 3] = s3 ? rsqrtf((float)s3) : 0.f;
}

__global__ void merge_dst_kernel(const unsigned* __restrict__ H, unsigned* __restrict__ P,
                                 int* __restrict__ cnt) {
    int i = blockIdx.x * blockDim.x + threadIdx.x;
    if (i >= NW) return;
    unsigned p0 = 0, p1 = 0, p2 = 0, p3 = 0;
    for (int b = 0; b < NB_H; ++b) {
        size_t idx = (size_t)b * NW + i;
        unsigned v = H[idx];
        P[idx] = p0 | (p1 << 8) | (p2 << 16) | (p3 << 24);
        p0 += v & 0xff; p1 += (v >> 8) & 0xff; p2 += (v >> 16) & 0xff; p3 += v >> 24;
    }
    cnt[4 * i + 0] = (int)p0; cnt[4 * i + 1] = (int)p1;
    cnt[4 * i + 2] = (int)p2; cnt[4 * i + 3] = (int)p3;
}

// ---- 3-phase scan ------------------------------------------------------

constexpr int SCAN_B = 256;
constexpr int SCAN_NB = (N_NODES + SCAN_B - 1) / SCAN_B;  // 196

__global__ void scan_block_kernel(const int* __restrict__ cnt, int* __restrict__ row,
                                  int* __restrict__ bsum) {
    __shared__ int buf[SCAN_B];
    int t = threadIdx.x;
    int i = blockIdx.x * SCAN_B + t;
    buf[t] = (i < N_NODES) ? cnt[i] : 0;
    __syncthreads();
    for (int off = 1; off < SCAN_B; off <<= 1) {
        int a = (t >= off) ? buf[t - off] : 0;
        __syncthreads();
        buf[t] += a;
        __syncthreads();
    }
    if (i < N_NODES) row[i + 1] = buf[t];
    if (t == SCAN_B - 1) bsum[blockIdx.x] = buf[t];
    if (i == 0) row[0] = 0;
}

__global__ void scan_sums_kernel(int* __restrict__ bsum) {
    __shared__ int buf[SCAN_NB];
    int t = threadIdx.x;
    if (t < SCAN_NB) buf[t] = bsum[t];
    __syncthreads();
    for (int off = 1; off < SCAN_NB; off <<= 1) {
        int a = (t >= off && t < SCAN_NB) ? buf[t - off] : 0;
        __syncthreads();
        if (t < SCAN_NB) buf[t] += a;
        __syncthreads();
    }
    if (t < SCAN_NB) bsum[t] = buf[t];
}

__global__ void scan_add_kernel(int* __restrict__ row, const int* __restrict__ bsum) {
    int i = blockIdx.x * SCAN_B + threadIdx.x;
    if (blockIdx.x > 0 && i < N_NODES) row[i + 1] += bsum[blockIdx.x - 1];
}

__global__ __launch_bounds__(256) void place_kernel(const int* __restrict__ src,
                                                    const int* __restrict__ dst,
                                                    const float* __restrict__ dinv,
                                                    const int* __restrict__ row,
                                                    const unsigned* __restrict__ P,
                                                    float2* __restrict__ csr) {
    __shared__ unsigned lds[NW];
    const int b = blockIdx.x, t = threadIdx.x;
    for (int i = t; i < NW; i += 256) lds[i] = 0;
    __syncthreads();
    const int e0 = b * EPB, e1 = e0 + EPB;
    const unsigned* Pb = P + (size_t)b * NW;
    for (int e = e0 + t; e < e1; e += 256) {
        int s = src[e], d = dst[e];
        if (s != d) {
            float w = -dinv[s] * dinv[d];
            int sh = 8 * (d & 3);
            unsigned old = atomicAdd(&lds[d >> 2], 1u << sh);
            unsigned cur = (old >> sh) & 0xff;
            unsigned pref = (Pb[d >> 2] >> sh) & 0xff;
            int pos = row[d] + (int)pref + (int)cur;
            csr[pos] = make_float2(w, __int_as_float(s));
        }
    }
}

// ---- L(z) gathers ------------------------------------------------------

// Layer 1 (F=4): thread per (node, feature) — 200K threads. Sequential
// per-(node,feature) fmaf order -> bit-exact.
__global__ void gatherF4_kernel(const int* __restrict__ row, const float2* __restrict__ csr,
                                const float* __restrict__ z, const float* __restrict__ prev,
                                float* __restrict__ out, float alpha, float beta) {
    int idx = blockIdx.x * blockDim.x + threadIdx.x;
    int node = idx >> 2;
    int lane = idx & 3;
    if (node >= N_NODES) return;
    int e0 = row[node], e1 = row[node + 1];
    float acc = 0.f;
#pragma unroll 4
    for (int e = e0; e < e1; ++e) {
        float2 ew = csr[e];  // 4 lanes same addr: hw broadcast
        acc = fmaf(ew.x, z[(size_t)__float_as_int(ew.y) * 4 + lane], acc);
    }
    float r = alpha * acc;
    if (beta != 0.f) r = fmaf(beta, prev[(size_t)node * 4 + lane], r);
    out[(size_t)node * 4 + lane] = r;
}

// Layers 2/3: 16-feature slice per XCD group, feature-blocked [NSLICE][N][16].
// Block = 128 threads = 32 nodes, 4-lane groups, float4 per lane.
// CSR staged into 1024-edge LDS windows (8 KB). Inner loop hand-batched:
// 4 edges' z rows loaded into named float4 temps (forces 4 loads in
// flight), then fmaf'd strictly in edge order -> bit-exact.
template <int NSLICE>
__global__ __launch_bounds__(128) void gather16_kernel(
        const int* __restrict__ row, const float2* __restrict__ csr,
        const float* __restrict__ z, const float* __restrict__ prev,
        float* __restrict__ out, float alpha, float beta) {
    constexpr int XPS = 8 / NSLICE;  // XCDs per slice
    constexpr int CAP = 1024;        // edges per LDS window (8 KB)
    __shared__ unsigned long long elds[CAP];
    const int bid = blockIdx.x;
    const int xcd = bid & 7;
    const int slice = xcd / XPS;
    const int sblk = (bid >> 3) * XPS + (xcd % XPS);
    if (sblk >= SB32) return;
    const int t = threadIdx.x;
    const int n = sblk * 32 + (t >> 2);  // 32 nodes per block, 4 lanes each
    const int lane = t & 3;              // feature quad within slice
    const bool valid = (n < N_NODES);
    const float* zs = z + (size_t)slice * N16 + 4 * lane;
    const int e0 = valid ? row[n] : 0;
    const int e1 = valid ? row[n + 1] : 0;
    const int nb0 = sblk * 32;
    const int b0 = row[nb0];
    const int b1 = row[min(nb0 + 32, N_NODES)];
    float4 acc = make_float4(0.f, 0.f, 0.f, 0.f);
    for (int w0 = b0; w0 < b1; w0 += CAP) {
        const int w1 = min(w0 + CAP, b1);
        __syncthreads();  // previous window fully consumed
        for (int e = w0 + t; e < w1; e += 128)
            elds[e - w0] = __builtin_nontemporal_load((const unsigned long long*)csr + e);
        __syncthreads();
        const int g0 = max(e0, w0), g1 = min(e1, w1);
        int e = g0;
        // 4-edge software pipeline: all 4 z-loads issued before the ordered
        // fmaf chain -> 4 outstanding VMEM per thread.
        for (; e + 4 <= g1; e += 4) {
            unsigned long long r0 = elds[e - w0];
            unsigned long long r1 = elds[e - w0 + 1];
            unsigned long long r2 = elds[e - w0 + 2];
            unsigned long long r3 = elds[e - w0 + 3];
            const float4 z0 = *(const float4*)(zs + (size_t)(int)(r0 >> 32) * 16);
            const float4 z1 = *(const float4*)(zs + (size_t)(int)(r1 >> 32) * 16);
            const float4 z2 = *(const float4*)(zs + (size_t)(int)(r2 >> 32) * 16);
            const float4 z3 = *(const float4*)(zs + (size_t)(int)(r3 >> 32) * 16);
            const float w_0 = __uint_as_float((unsigned)r0);
            const float w_1 = __uint_as_float((unsigned)r1);
            const float w_2 = __uint_as_float((unsigned)r2);
            const float w_3 = __uint_as_float((unsigned)r3);
            acc.x = fmaf(w_0, z0.x, acc.x); acc.y = fmaf(w_0, z0.y, acc.y);
            acc.z = fmaf(w_0, z0.z, acc.z); acc.w = fmaf(w_0, z0.w, acc.w);
            acc.x = fmaf(w_1, z1.x, acc.x); acc.y = fmaf(w_1, z1.y, acc.y);
            acc.z = fmaf(w_1, z1.z, acc.z); acc.w = fmaf(w_1, z1.w, acc.w);
            acc.x = fmaf(w_2, z2.x, acc.x); acc.y = fmaf(w_2, z2.y, acc.y);
            acc.z = fmaf(w_2, z2.z, acc.z); acc.w = fmaf(w_2, z2.w, acc.w);
            acc.x = fmaf(w_3, z3.x, acc.x); acc.y = fmaf(w_3, z3.y, acc.y);
            acc.z = fmaf(w_3, z3.z, acc.z); acc.w = fmaf(w_3, z3.w, acc.w);
        }
        for (; e < g1; ++e) {
            unsigned long long raw = elds[e - w0];
            float w = __uint_as_float((unsigned)raw);
            int s = (int)(raw >> 32);
            const float4 zz = *(const float4*)(zs + (size_t)s * 16);
            acc.x = fmaf(w, zz.x, acc.x);
            acc.y = fmaf(w, zz.y, acc.y);
            acc.z = fmaf(w, zz.z, acc.z);
            acc.w = fmaf(w, zz.w, acc.w);
        }
    }
    if (valid) {
        float4 r = make_float4(alpha * acc.x, alpha * acc.y,
                               alpha * acc.z, alpha * acc.w);
        size_t off = (size_t)slice * N16 + (size_t)n * 16 + 4 * lane;
        if (beta != 0.f) {
            r.x = fmaf(beta, __builtin_nontemporal_load(prev + off), r.x);
            r.y = fmaf(beta, __builtin_nontemporal_load(prev + off + 1), r.y);
            r.z = fmaf(beta, __builtin_nontemporal_load(prev + off + 2), r.z);
            r.w = fmaf(beta, __builtin_nontemporal_load(prev + off + 3), r.w);
        }
        __builtin_nontemporal_store(r.x, out + off);
        __builtin_nontemporal_store(r.y, out + off + 1);
        __builtin_nontemporal_store(r.z, out + off + 2);
        __builtin_nontemporal_store(r.w, out + off + 3);
    }
}

// ---- combine: out[n,o] = relu(b[o] + sum_k T_k[n,:] @ W[k,:,o]) --------
// Inputs X,T1..T4 are feature-blocked [FI/16][N][16]; output written blocked
// [FO/16][N][16]. Blocked output also makes the layer-3 in-place write to T1
// race-free: each block writes exactly the (node,slice) bytes it staged.

template <int FI>
__global__ __launch_bounds__(256, 4) void combine64_kernel(
        const float* __restrict__ X, const float* __restrict__ T1,
        const float* __restrict__ T2, const float* __restrict__ T3,
        const float* __restrict__ T4, const float* __restrict__ W,
        const float* __restrict__ b, float* __restrict__ out) {
    constexpr int FO = 64;
    constexpr int TS = FI + 4;
    __shared__ float Ts[64 * TS];
    __shared__ float Ws[FI * FO];
    const int t = threadIdx.x;
    const int tn = t & 15;
    const int to = t >> 4;
    const int n_base = blockIdx.x * 64;
    const float* Tk[5] = {X, T1, T2, T3, T4};

    float acc[4][4];
    {
        const float4 bb = *(const float4*)(b + 4 * to);
#pragma unroll
        for (int i = 0; i < 4; ++i) {
            acc[i][0] = bb.x; acc[i][1] = bb.y; acc[i][2] = bb.z; acc[i][3] = bb.w;
        }
    }

#pragma unroll
    for (int k = 0; k < 5; ++k) {
        __syncthreads();
        {
            const float* base = Tk[k];
            constexpr int NV = 64 * FI / 4;
#pragma unroll
            for (int idx = t; idx < NV; idx += 256) {
                int r = idx / (FI / 4), c = idx % (FI / 4);
                int s = c >> 2;            // feature block (16-wide)
                int j = (c & 3) * 4;       // offset within block
                float4 v = make_float4(0.f, 0.f, 0.f, 0.f);
                if (n_base + r < N_NODES)
                    v = *(const float4*)(base + (size_t)s * N16 +
                                         (size_t)(n_base + r) * 16 + j);
                *(float4*)(Ts + r * TS + 4 * c) = v;  // f = 16*s + j = 4*c
            }
            const float4* w4 = (const float4*)(W + (size_t)k * FI * FO);
            constexpr int WV = FI * FO / 4;
#pragma unroll
            for (int idx = t; idx < WV; idx += 256) *(float4*)(Ws + 4 * idx) = w4[idx];
        }
        __syncthreads();
#pragma unroll 4
        for (int f0 = 0; f0 < FI; f0 += 4) {
            float tv[4][4];
#pragma unroll
            for (int i = 0; i < 4; ++i) {
                float4 q = *(const float4*)(Ts + (tn + 16 * i) * TS + f0);
                tv[i][0] = q.x; tv[i][1] = q.y; tv[i][2] = q.z; tv[i][3] = q.w;
            }
#pragma unroll
            for (int j = 0; j < 4; ++j) {
                float4 w = *(const float4*)(Ws + (f0 + j) * FO + 4 * to);
#pragma unroll
                for (int i = 0; i < 4; ++i) {
                    acc[i][0] = fmaf(tv[i][j], w.x, acc[i][0]);
                    acc[i][1] = fmaf(tv[i][j], w.y, acc[i][1]);
                    acc[i][2] = fmaf(tv[i][j], w.z, acc[i][2]);
                    acc[i][3] = fmaf(tv[i][j], w.w, acc[i][3]);
                }
            }
        }
    }
    __syncthreads();
#pragma unroll
    for (int i = 0; i < 4; ++i) {
        int n = n_base + tn + 16 * i;
        if (n < N_NODES) {
            float4 r = make_float4(fmaxf(acc[i][0], 0.f), fmaxf(acc[i][1], 0.f),
                                   fmaxf(acc[i][2], 0.f), fmaxf(acc[i][3], 0.f));
            int s = to >> 2;            // output feature block
            int j = (to & 3) * 4;
            *(float4*)(out + (size_t)s * N16 + (size_t)n * 16 + j) = r;
        }
    }
}

// Layer 1 combine: X,T row-major [N][4], output blocked [2][N][16].
__global__ void combine432_kernel(const float* __restrict__ X, const float* __restrict__ T1,
                                  const float* __restrict__ T2, const float* __restrict__ T3,
                                  const float* __restrict__ T4, const float* __restrict__ W,
                                  const float* __restrict__ b, float* __restrict__ out) {
    __shared__ float Ws[5 * 4 * 32];
    int t = threadIdx.x;
    for (int i = t; i < 5 * 4 * 32; i += 256) Ws[i] = W[i];
    __syncthreads();
    int node = blockIdx.x * 8 + (t >> 5);
    int o = t & 31;
    if (node >= N_NODES) return;
    const float4* Tk[5] = {(const float4*)X, (const float4*)T1, (const float4*)T2,
                           (const float4*)T3, (const float4*)T4};
    float acc = b[o];
#pragma unroll
    for (int k = 0; k < 5; ++k) {
        float4 q = Tk[k][node];
        const float* w = Ws + k * 128 + o;
        acc = fmaf(q.x, w[0], acc);
        acc = fmaf(q.y, w[32], acc);
        acc = fmaf(q.z, w[64], acc);
        acc = fmaf(q.w, w[96], acc);
    }
    out[(size_t)(o >> 4) * N16 + (size_t)node * 16 + (o & 15)] = fmaxf(acc, 0.f);
}

// ---- pooling + MLP -----------------------------------------------------

// h is feature-blocked [4][N][16] (layer-3 output).
__global__ void pool_kernel(const float* __restrict__ h, const int* __restrict__ batch,
                            float* __restrict__ pooled, float* __restrict__ cntf) {
    int wid = blockIdx.x * (blockDim.x / 64) + (threadIdx.x >> 6);
    int lane = threadIdx.x & 63;
    int nwaves = gridDim.x * (blockDim.x / 64);
    int per = (N_NODES + nwaves - 1) / nwaves;
    int n0 = wid * per;
    int n1 = min(n0 + per, N_NODES);
    if (n0 >= n1) return;
    const float* hp = h + (size_t)(lane >> 4) * N16 + (lane & 15);
    int cur = batch[n0];
    float acc = 0.f;
    int c = 0;
    for (int n = n0; n < n1; ++n) {
        int g = batch[n];
        if (g != cur) {
            atomicAdd(&pooled[cur * 64 + lane], acc);
            if (lane == 0) atomicAdd(&cntf[cur], (float)c);
            acc = 0.f; c = 0; cur = g;
        }
        acc += hp[(size_t)n * 16];
        ++c;
    }
    atomicAdd(&pooled[cur * 64 + lane], acc);
    if (lane == 0) atomicAdd(&cntf[cur], (float)c);
}

__global__ void fc_kernel(const float* __restrict__ pooled, const float* __restrict__ cnt,
                          const float* __restrict__ w1, const float* __restrict__ b1,
                          const float* __restrict__ w2, const float* __restrict__ b2,
                          float* __restrict__ out) {
    int g = blockIdx.x;
    int t = threadIdx.x;
    __shared__ float hid[32];
    float c = fmaxf(cnt[g], 1.0f);
    float acc = b1[t];
    for (int f = 0; f < 64; ++f) acc = fmaf(pooled[g * 64 + f] / c, w1[f * 32 + t], acc);
    hid[t] = fmaxf(acc, 0.f);
    __syncthreads();
    if (t == 0) {
        float acc2 = b2[0];
        for (int o = 0; o < 32; ++o) acc2 = fmaf(hid[o], w2[o], acc2);
        out[g] = acc2;
    }
}

// ---- host orchestration ------------------------------------------------

template <int FI, int FO>
static void run_layer(const int* row, const float2* csr, const float* X,
                      float* T1, float* T2, float* T3, float* T4,
                      const float* W, const float* b, float* out, hipStream_t stream) {
    if constexpr (FI == 4) {
        dim3 g(cdiv((long long)N_NODES * 4, 256)), blk(256);
        hipLaunchKernelGGL(gatherF4_kernel, g, blk, 0, stream, row, csr, X,  X,  T1, 1.f, 0.f);
        hipLaunchKernelGGL(gatherF4_kernel, g, blk, 0, stream, row, csr, T1, X,  T2, 2.f, -1.f);
        hipLaunchKernelGGL(gatherF4_kernel, g, blk, 0, stream, row, csr, T2, T1, T3, 2.f, -1.f);
        hipLaunchKernelGGL(gatherF4_kernel, g, blk, 0, stream, row, csr, T3, T2, T4, 2.f, -1.f);
    } else {
        constexpr int NSLICE = FI / 16;
        constexpr int XPS = 8 / NSLICE;
        dim3 g(cdiv(SB32, XPS) * 8), blk(128);
        hipLaunchKernelGGL((gather16_kernel<NSLICE>), g, blk, 0, stream, row, csr, X,  X,  T1, 1.f, 0.f);
        hipLaunchKernelGGL((gather16_kernel<NSLICE>), g, blk, 0, stream, row, csr, T1, X,  T2, 2.f, -1.f);
        hipLaunchKernelGGL((gather16_kernel<NSLICE>), g, blk, 0, stream, row, csr, T2, T1, T3, 2.f, -1.f);
        hipLaunchKernelGGL((gather16_kernel<NSLICE>), g, blk, 0, stream, row, csr, T3, T2, T4, 2.f, -1.f);
    }
    if constexpr (FO == 64) {
        hipLaunchKernelGGL((combine64_kernel<FI>), dim3(cdiv(N_NODES, 64)), dim3(256), 0,
                           stream, X, T1, T2, T3, T4, W, b, out);
    } else {
        hipLaunchKernelGGL(combine432_kernel, dim3(cdiv(N_NODES, 8)), dim3(256), 0,
                           stream, X, T1, T2, T3, T4, W, b, out);
    }
}

extern "C" void kernel_launch(void* const* d_in, const int* in_sizes, int n_in,
                              void* d_out, int out_size, void* d_ws, size_t ws_size,
                              hipStream_t stream) {
    const float* x    = (const float*)d_in[0];
    const int*   ei   = (const int*)d_in[1];
    const int*   batch= (const int*)d_in[2];
    const float* W1   = (const float*)d_in[4];
    const float* b1   = (const float*)d_in[5];
    const float* W2   = (const float*)d_in[6];
    const float* b2   = (const float*)d_in[7];
    const float* W3   = (const float*)d_in[8];
    const float* b3   = (const float*)d_in[9];
    const float* fcw1 = (const float*)d_in[10];
    const float* fcb1 = (const float*)d_in[11];
    const float* fcw2 = (const float*)d_in[12];
    const float* fcb2 = (const float*)d_in[13];

    const int* src = ei;
    const int* dst = ei + N_EDGES;

    float* base = (float*)d_ws;
    float*  dinv   = base + 0;                      // 50000
    int*    cnt_i  = (int*)(base + 50000);          // 50000
    int*    row    = (int*)(base + 100000);         // 50004
    int*    bsum   = (int*)(base + 150004);         // 252
    float2* csr    = (float2*)(base + 150256);      // 1.6M float2
    float*  T1     = base + 3350256;
    float*  T2     = base + 6550256;
    float*  T3     = base + 9750256;
    float*  T4     = base + 12950256;
    float*  H1     = T4 + 1600000;                  // layer1 out, blocked [2][N][16]
    float*  H2     = base + 16150256;               // layer2 out, blocked [4][N][16]
    float*  pooled = base + 19350256;
    float*  cntf   = base + 19358448;

    unsigned* Hs = (unsigned*)T1;  // build-phase scratch aliases T1..T3
    unsigned* Hd = (unsigned*)T2;
    unsigned* P  = (unsigned*)T3;

    hipLaunchKernelGGL(hist2_kernel, dim3(NB_H), dim3(256), 2 * NW * sizeof(unsigned),
                       stream, src, dst, Hs, Hd);
    hipLaunchKernelGGL(merge_src_kernel, dim3(cdiv(NW, 256)), dim3(256), 0, stream, Hs, dinv);
    hipLaunchKernelGGL(merge_dst_kernel, dim3(cdiv(NW, 256)), dim3(256), 0, stream, Hd, P, cnt_i);
    hipLaunchKernelGGL(scan_block_kernel, dim3(SCAN_NB), dim3(SCAN_B), 0, stream, cnt_i, row, bsum);
    hipLaunchKernelGGL(scan_sums_kernel, dim3(1), dim3(256), 0, stream, bsum);
    hipLaunchKernelGGL(scan_add_kernel, dim3(SCAN_NB), dim3(SCAN_B), 0, stream, row, bsum);
    hipLaunchKernelGGL(place_kernel, dim3(NB_H), dim3(256), 0, stream,
                       src, dst, dinv, row, P, csr);

    run_layer<4, 32>(row, csr, x,  T1, T2, T3, T4, W1, b1, H1, stream);
    run_layer<32, 64>(row, csr, H1, T1, T2, T3, T4, W2, b2, H2, stream);
    // layer 3 writes blocked output in place into T1 (race-free: each combine
    // block writes exactly the node rows/slices it staged).
    run_layer<64, 64>(row, csr, H2, T1, T2, T3, T4, W3, b3, T1, stream);

    hipMemsetAsync(pooled, 0, (8192 + 128) * sizeof(float), stream);
    hipLaunchKernelGGL(pool_kernel, dim3(128), dim3(256), 0, stream, T1, batch, pooled, cntf);
    hipLaunchKernelGGL(fc_kernel, dim3(N_GRAPHS), dim3(32), 0, stream,
                       pooled, cntf, fcw1, fcb1, fcw2, fcb2, (float*)d_out);
}